// Round 4
// baseline (126.277 us; speedup 1.0000x reference)
//
#include <hip/hip_runtime.h>

// Periodogram: out[b,m] = (re^2 + im^2)/N
//   re = sum_n a[b,n]*cos(2pi*xg[m]*n) + b[b,n]*sin(2pi*xg[m]*n)
//   im = sum_n b[b,n]*cos(2pi*xg[m]*n) - a[b,n]*sin(2pi*xg[m]*n)
// f16 MFMA GEMMs; trig generated in registers via rotation recurrence
// (no transcendentals / no LDS for the trig side in the K-loop).

typedef __fp16 half8 __attribute__((ext_vector_type(8)));
typedef __fp16 half2v __attribute__((ext_vector_type(2)));
typedef float f32x4 __attribute__((ext_vector_type(4)));

#define B_SZ 512
#define N_SZ 1024
#define M_SZ 16384
#define BT 128
#define MT 128
#define KC 64   // K-chunk staged in LDS
#define KS 32   // K per MFMA step

union H8 { half8 v; half2v h2[4]; };
union U4 { half2v h2[4]; uint4 u; };

// LDS layout per array (a,b), per K-64 chunk, fragment-linear f16:
//   block(rb = row>>4 in 0..7, kh = k32-half in 0..1) = 1024 B at (rb*2+kh)*1024
//   cell(g = (k&31)>>3, row16 = row&15) = 16 B at (g*16+row16)*16, holding
//   k = kh*32 + g*8 + {0..7}. Frag read: lane l -> cell l (addr = block + l*16),
//   i.e. row16 = l&15, g = l>>4 — the convention validated in round 3.
//   Both b128 reads and b128 writes hit 8 lanes per 4-bank group = phased,
//   conflict-free.

__global__ __launch_bounds__(256, 2)
void periodogram_kernel(const float* __restrict__ x, const float* __restrict__ xgrid,
                        float* __restrict__ out) {
    __shared__ __align__(16) unsigned char smem[2 * 16384];  // A | B arrays, 16 KB each
    const int tid  = (int)threadIdx.x;
    const int lane = tid & 63;
    const int w    = tid >> 6;
    const int b0 = ((int)blockIdx.x & 3) * BT;
    const int m0 = ((int)blockIdx.x >> 2) * MT;

    const int wr = (w >> 1) * 64;   // wave row offset in tile
    const int wc = (w & 1) * 64;    // wave col offset in tile

    // ---------------- trig state init (once) ----------------
    // lane l (col = l&15 within fn-block) holds k = g8 + j, g8 = (l>>4)*8.
    const float g8f = (float)((lane >> 4) << 3);
    float cb[4], sb[4], C1[4], S1[4], C32[4], S32[4];
#pragma unroll
    for (int fn = 0; fn < 4; ++fn) {
        const float xg = xgrid[m0 + wc + fn * 16 + (lane & 15)];
        float p1 = xg - floorf(xg);
        C1[fn] = __builtin_amdgcn_cosf(p1);          // rotate by Delta-k = 1
        S1[fn] = __builtin_amdgcn_sinf(p1);
        float p32 = xg * 32.0f; p32 -= floorf(p32);  // exact product (x32)
        C32[fn] = __builtin_amdgcn_cosf(p32);        // rotate by Delta-k = 32
        S32[fn] = __builtin_amdgcn_sinf(p32);
        float pb = xg * g8f; pb -= floorf(pb);
        cb[fn] = __builtin_amdgcn_cosf(pb);          // state at k = g8
        sb[fn] = __builtin_amdgcn_sinf(pb);
    }

    f32x4 accRe[4][4], accIm[4][4];
#pragma unroll
    for (int i = 0; i < 4; ++i)
#pragma unroll
        for (int j = 0; j < 4; ++j) { accRe[i][j] = (f32x4)0.0f; accIm[i][j] = (f32x4)0.0f; }

    // ---------------- staging assignment ----------------
    const int srow = tid >> 1;          // 0..127
    const int skh  = tid & 1;           // which 32-k half of the chunk
    const float* srcA = x + (size_t)(b0 + srow) * 2048 + (size_t)(skh * 32);
    const float* srcB = srcA + 1024;
    const unsigned wbase = (unsigned)(((srow >> 4) * 2 + skh) * 1024 + ((srow & 15) << 4));

    const unsigned rbaseW = (unsigned)((wr >> 4) * 2048 + (lane << 4));

    for (int ch = 0; ch < N_SZ / KC; ++ch) {
        const int k0c = ch * KC;
        __syncthreads();   // previous chunk's reads done
        // ---------------- stage chunk (a,b) as f16 ----------------
        {
            const float4* pa = (const float4*)(srcA + k0c);
            const float4* pb = (const float4*)(srcB + k0c);
#pragma unroll
            for (int g = 0; g < 4; ++g) {
                const float4 v0 = pa[2 * g], v1 = pa[2 * g + 1];
                U4 u;
                u.h2[0] = __builtin_amdgcn_cvt_pkrtz(v0.x, v0.y);
                u.h2[1] = __builtin_amdgcn_cvt_pkrtz(v0.z, v0.w);
                u.h2[2] = __builtin_amdgcn_cvt_pkrtz(v1.x, v1.y);
                u.h2[3] = __builtin_amdgcn_cvt_pkrtz(v1.z, v1.w);
                *(uint4*)(smem + wbase + g * 256) = u.u;
            }
#pragma unroll
            for (int g = 0; g < 4; ++g) {
                const float4 v0 = pb[2 * g], v1 = pb[2 * g + 1];
                U4 u;
                u.h2[0] = __builtin_amdgcn_cvt_pkrtz(v0.x, v0.y);
                u.h2[1] = __builtin_amdgcn_cvt_pkrtz(v0.z, v0.w);
                u.h2[2] = __builtin_amdgcn_cvt_pkrtz(v1.x, v1.y);
                u.h2[3] = __builtin_amdgcn_cvt_pkrtz(v1.z, v1.w);
                *(uint4*)(smem + 16384 + wbase + g * 256) = u.u;
            }
        }
        __syncthreads();
        // ---------------- compute: 2 K-32 steps ----------------
#pragma unroll
        for (int s = 0; s < 2; ++s) {
            const unsigned ab = rbaseW + (unsigned)(s * 1024);
            half8 fa[4], fb[4];
#pragma unroll
            for (int fm = 0; fm < 4; ++fm) {
                fa[fm] = *(const half8*)(smem + ab + fm * 2048);
                fb[fm] = *(const half8*)(smem + 16384 + ab + fm * 2048);
            }
#pragma unroll
            for (int fn = 0; fn < 4; ++fn) {
                // generate B fragments (8 k-consecutive trig values) by
                // rotating (cb,sb) with the Delta-k=1 rotation
                H8 fc, fs, fns;
                float cj = cb[fn], sj = sb[fn];
#pragma unroll
                for (int jp = 0; jp < 4; ++jp) {
                    const float t1 = sj * S1[fn];
                    const float co = __builtin_fmaf(cj, C1[fn], -t1);
                    const float t2 = cj * S1[fn];
                    const float so = __builtin_fmaf(sj, C1[fn], t2);
                    fc.h2[jp]  = __builtin_amdgcn_cvt_pkrtz(cj, co);
                    fs.h2[jp]  = __builtin_amdgcn_cvt_pkrtz(sj, so);
                    fns.h2[jp] = __builtin_amdgcn_cvt_pkrtz(-sj, -so);
                    const float t3 = so * S1[fn];
                    cj = __builtin_fmaf(co, C1[fn], -t3);
                    const float t4 = co * S1[fn];
                    sj = __builtin_fmaf(so, C1[fn], t4);
                }
#pragma unroll
                for (int fm = 0; fm < 4; ++fm) {
                    accRe[fm][fn] = __builtin_amdgcn_mfma_f32_16x16x32_f16(fa[fm], fc.v,  accRe[fm][fn], 0, 0, 0);
                    accRe[fm][fn] = __builtin_amdgcn_mfma_f32_16x16x32_f16(fb[fm], fs.v,  accRe[fm][fn], 0, 0, 0);
                    accIm[fm][fn] = __builtin_amdgcn_mfma_f32_16x16x32_f16(fb[fm], fc.v,  accIm[fm][fn], 0, 0, 0);
                    accIm[fm][fn] = __builtin_amdgcn_mfma_f32_16x16x32_f16(fa[fm], fns.v, accIm[fm][fn], 0, 0, 0);
                }
                // advance base state by Delta-k = 32 for next K-step
                const float r1 = sb[fn] * S32[fn];
                const float ncb = __builtin_fmaf(cb[fn], C32[fn], -r1);
                const float r2 = cb[fn] * S32[fn];
                const float nsb = __builtin_fmaf(sb[fn], C32[fn], r2);
                cb[fn] = ncb; sb[fn] = nsb;
            }
        }
    }

    // ---------------- epilogue: out = (re^2 + im^2)/N ----------------
    // D frag layout (measured m89): col = lane&15, row = (lane>>4)*4 + reg
    const float inv = 1.0f / (float)N_SZ;
    const int orow0 = b0 + wr + ((lane >> 4) << 2);
    const int ocol0 = m0 + wc + (lane & 15);
#pragma unroll
    for (int fm = 0; fm < 4; ++fm)
#pragma unroll
        for (int fn = 0; fn < 4; ++fn) {
            const f32x4 r = accRe[fm][fn];
            const f32x4 im = accIm[fm][fn];
            const int col = ocol0 + fn * 16;
#pragma unroll
            for (int j = 0; j < 4; ++j) {
                const int row = orow0 + fm * 16 + j;
                out[(size_t)row * M_SZ + col] = (r[j] * r[j] + im[j] * im[j]) * inv;
            }
        }
}

extern "C" void kernel_launch(void* const* d_in, const int* in_sizes, int n_in,
                              void* d_out, int out_size, void* d_ws, size_t ws_size,
                              hipStream_t stream) {
    const float* x     = (const float*)d_in[0];
    const float* xgrid = (const float*)d_in[1];
    float* out = (float*)d_out;
    dim3 grid(B_SZ / BT * (M_SZ / MT));   // 4 * 128 = 512 blocks
    dim3 block(256);
    periodogram_kernel<<<grid, block, 0, stream>>>(x, xgrid, out);
}

// Round 6
// 67.238 us; speedup vs baseline: 1.8781x; 1.8781x over previous
//
#include <hip/hip_runtime.h>

// Periodogram: out[b,m] = (re^2 + im^2)/N,  re = aC + bS, im = bC - aS
// f16 MFMA GEMMs. Trig staged to LDS (round-3 skeleton), but generated by a
// per-thread Delta-rotation recurrence (no per-step transcendentals), with
// XOR-swizzled conflict-free LDS cells and NS-by-XOR after fragment read.

typedef __fp16 half8 __attribute__((ext_vector_type(8)));
typedef __fp16 half2v __attribute__((ext_vector_type(2)));
typedef float f32x4 __attribute__((ext_vector_type(4)));

#define B_SZ 512
#define N_SZ 1024
#define M_SZ 16384
#define BT 128
#define MT 128
#define KT 32

union U2  { half2v h2[2]; uint2 u; };
union H8U { half8 v; uint4 u; };

// LDS cell layout per array, [128 rows][32 k] f16, 8 KB:
//   rb = row>>4 selects a 1 KB block; cell c = g*16 + row16 (g = k>>3).
//   Swizzle: c' = c ^ (g<<1)  (XOR into row16 bits 1-2) applied on BOTH
//   write and read -> bank-balanced writes (8B) and reads (16B), and the
//   lane->cell fragment convention is unchanged (permutation argument).
//   Within cell: byte (k&7)*2.

__global__ __launch_bounds__(256, 2)
void periodogram_kernel(const float* __restrict__ x, const float* __restrict__ xgrid,
                        float* __restrict__ out) {
    __shared__ __align__(16) unsigned char smem[4 * 8192];  // A | B | C | S
    const int tid  = (int)threadIdx.x;
    const int lane = tid & 63;
    const int w    = tid >> 6;
    const int b0 = ((int)blockIdx.x & 3) * BT;
    const int m0 = ((int)blockIdx.x >> 2) * MT;

    // ---- staging assignment: thread -> rows {row8+32*rep}, k-chunk kk ----
    const int row8 = tid >> 3;          // 0..31
    const int kk   = (tid & 7) * 4;     // 0,4,...,28
    const int g    = kk >> 3;           // 0..3
    const int kkh  = (kk >> 2) & 1;     // which 8B half of the 16B cell

    unsigned woff[4];
    const float* srcA[4];
    float C1[4], S1[4], C32[4], S32[4], c0v[4], s0v[4];
#pragma unroll
    for (int rep = 0; rep < 4; ++rep) {
        const int row = row8 + rep * 32;
        const int rb = row >> 4, r16 = row & 15;
        woff[rep] = (unsigned)(rb * 1024 + ((g * 16 + (r16 ^ (g << 1))) << 4) + kkh * 8);
        srcA[rep] = x + (size_t)(b0 + row) * 2048 + kk;
        const float xg = xgrid[m0 + row];
        // Delta-1 rotation (per k)
        const float f1 = xg - floorf(xg);
        C1[rep] = __builtin_amdgcn_cosf(f1);
        S1[rep] = __builtin_amdgcn_sinf(f1);
        // Delta-32 rotation (per K-step); xg*32 is exact
        float p32 = xg * 32.0f; p32 -= floorf(p32);
        C32[rep] = __builtin_amdgcn_cosf(p32);
        S32[rep] = __builtin_amdgcn_sinf(p32);
        // state at k = kk (residual-corrected phase)
        const float kf = (float)kk;
        const float pk = xg * kf;
        const float e  = __builtin_fmaf(xg, kf, -pk);
        const float f  = (pk - floorf(pk)) + e;
        c0v[rep] = __builtin_amdgcn_cosf(f);
        s0v[rep] = __builtin_amdgcn_sinf(f);
    }

    f32x4 accRe[4][4], accIm[4][4];
#pragma unroll
    for (int i = 0; i < 4; ++i)
#pragma unroll
        for (int j = 0; j < 4; ++j) { accRe[i][j] = (f32x4)0.0f; accIm[i][j] = (f32x4)0.0f; }

    // ---- fragment read bases (swizzled lane->cell) ----
    const int wr = (w >> 1) * 64;
    const int wc = (w & 1) * 64;
    const unsigned roff  = (unsigned)((lane ^ ((lane >> 4) << 1)) << 4);
    const unsigned aBase = 0u     + ((unsigned)(wr >> 4) << 10) + roff;
    const unsigned bBase = 8192u  + ((unsigned)(wr >> 4) << 10) + roff;
    const unsigned cBase = 16384u + ((unsigned)(wc >> 4) << 10) + roff;
    const unsigned sBase = 24576u + ((unsigned)(wc >> 4) << 10) + roff;

    for (int t = 0; t < N_SZ / KT; ++t) {
        const int k0 = t * KT;
        // ---- issue global loads + trig VALU before the barrier ----
        float4 va[4], vb[4];
#pragma unroll
        for (int rep = 0; rep < 4; ++rep) {
            va[rep] = *(const float4*)(srcA[rep] + k0);
            vb[rep] = *(const float4*)(srcA[rep] + k0 + 1024);
        }
        uint2 cw[4], sw[4];
#pragma unroll
        for (int rep = 0; rep < 4; ++rep) {
            const float c0 = c0v[rep], s0 = s0v[rep];
            const float c1 = __builtin_fmaf(c0, C1[rep], -(s0 * S1[rep]));
            const float s1 = __builtin_fmaf(s0, C1[rep],  (c0 * S1[rep]));
            const float c2 = __builtin_fmaf(c1, C1[rep], -(s1 * S1[rep]));
            const float s2 = __builtin_fmaf(s1, C1[rep],  (c1 * S1[rep]));
            const float c3 = __builtin_fmaf(c2, C1[rep], -(s2 * S1[rep]));
            const float s3 = __builtin_fmaf(s2, C1[rep],  (c2 * S1[rep]));
            U2 pc, ps;
            pc.h2[0] = __builtin_amdgcn_cvt_pkrtz(c0, c1);
            pc.h2[1] = __builtin_amdgcn_cvt_pkrtz(c2, c3);
            ps.h2[0] = __builtin_amdgcn_cvt_pkrtz(s0, s1);
            ps.h2[1] = __builtin_amdgcn_cvt_pkrtz(s2, s3);
            cw[rep] = pc.u; sw[rep] = ps.u;
            // advance state by Delta-32
            c0v[rep] = __builtin_fmaf(c0, C32[rep], -(s0 * S32[rep]));
            s0v[rep] = __builtin_fmaf(s0, C32[rep],  (c0 * S32[rep]));
        }
        __syncthreads();   // previous iteration's fragment reads done
        // ---- stage to LDS ----
#pragma unroll
        for (int rep = 0; rep < 4; ++rep) {
            U2 pa, pb;
            pa.h2[0] = __builtin_amdgcn_cvt_pkrtz(va[rep].x, va[rep].y);
            pa.h2[1] = __builtin_amdgcn_cvt_pkrtz(va[rep].z, va[rep].w);
            pb.h2[0] = __builtin_amdgcn_cvt_pkrtz(vb[rep].x, vb[rep].y);
            pb.h2[1] = __builtin_amdgcn_cvt_pkrtz(vb[rep].z, vb[rep].w);
            *(uint2*)(smem + 0     + woff[rep]) = pa.u;
            *(uint2*)(smem + 8192  + woff[rep]) = pb.u;
            *(uint2*)(smem + 16384 + woff[rep]) = cw[rep];
            *(uint2*)(smem + 24576 + woff[rep]) = sw[rep];
        }
        __syncthreads();
        // ---- compute ----
        half8 fa[4], fb[4];
#pragma unroll
        for (int fm = 0; fm < 4; ++fm) {
            fa[fm] = *(const half8*)(smem + aBase + fm * 1024);
            fb[fm] = *(const half8*)(smem + bBase + fm * 1024);
        }
#pragma unroll
        for (int fn = 0; fn < 4; ++fn) {
            const half8 fc = *(const half8*)(smem + cBase + fn * 1024);
            H8U fsU;  fsU.v = *(const half8*)(smem + sBase + fn * 1024);
            H8U fnsU;
            fnsU.u.x = fsU.u.x ^ 0x80008000u;
            fnsU.u.y = fsU.u.y ^ 0x80008000u;
            fnsU.u.z = fsU.u.z ^ 0x80008000u;
            fnsU.u.w = fsU.u.w ^ 0x80008000u;
#pragma unroll
            for (int fm = 0; fm < 4; ++fm) {
                accRe[fm][fn] = __builtin_amdgcn_mfma_f32_16x16x32_f16(fa[fm], fc,     accRe[fm][fn], 0, 0, 0);
                accRe[fm][fn] = __builtin_amdgcn_mfma_f32_16x16x32_f16(fb[fm], fsU.v,  accRe[fm][fn], 0, 0, 0);
                accIm[fm][fn] = __builtin_amdgcn_mfma_f32_16x16x32_f16(fb[fm], fc,     accIm[fm][fn], 0, 0, 0);
                accIm[fm][fn] = __builtin_amdgcn_mfma_f32_16x16x32_f16(fa[fm], fnsU.v, accIm[fm][fn], 0, 0, 0);
            }
        }
    }

    // ---- epilogue: out = (re^2 + im^2)/N ----
    // D frag layout (measured m89): col = lane&15, row = (lane>>4)*4 + reg
    const float inv = 1.0f / (float)N_SZ;
    const int orow0 = b0 + wr + ((lane >> 4) << 2);
    const int ocol0 = m0 + wc + (lane & 15);
#pragma unroll
    for (int fm = 0; fm < 4; ++fm)
#pragma unroll
        for (int fn = 0; fn < 4; ++fn) {
            const f32x4 r = accRe[fm][fn];
            const f32x4 im = accIm[fm][fn];
            const int col = ocol0 + fn * 16;
#pragma unroll
            for (int j = 0; j < 4; ++j) {
                const int row = orow0 + fm * 16 + j;
                out[(size_t)row * M_SZ + col] = (r[j] * r[j] + im[j] * im[j]) * inv;
            }
        }
}

extern "C" void kernel_launch(void* const* d_in, const int* in_sizes, int n_in,
                              void* d_out, int out_size, void* d_ws, size_t ws_size,
                              hipStream_t stream) {
    const float* x     = (const float*)d_in[0];
    const float* xgrid = (const float*)d_in[1];
    float* out = (float*)d_out;
    dim3 grid(B_SZ / BT * (M_SZ / MT));   // 4 * 128 = 512 blocks
    dim3 block(256);
    periodogram_kernel<<<grid, block, 0, stream>>>(x, xgrid, out);
}